// Round 13
// baseline (576.131 us; speedup 1.0000x reference)
//
#include <hip/hip_runtime.h>
#include <cstdint>
#include <cstddef>

// CRF loss: out[b] = log_norm(b) - target_score(b).  B=512, N=1024, K=64.
//
// R13 vs R12: burner removed (R12 refuted DVFS theory: +busy -> slower).
// R11/R12 counters show ~550 of 716 cyc/step is dependency STALL on one
// serial chain (active-CU VALUBusy 17%, MfmaUtil 4%). Lever: overlap two
// INDEPENDENT recurrence chains per wave (rows 0-15 = chain A, rows
// 16-31 = chain B, shared E^T fragments). B's issue fills A's stalls.
// MFMA pairs back to srcC-chained (add removed; bubble hidden by the
// other chain). vmcnt ring: 7-deep x 8 loads/step, steady wait
// vmcnt(40), max 56 in flight (<63 cap).
//
// Per-chain numerics BIT-IDENTICAL to R11 (absmax 32): state+E f16,
// mfma_f32_16x16x32_f16, psi(blk,q) A-map matching C->B pack,
// pe = exp2(emit*LOG2E - s), lag-1 s via __shfl, CHI=60000 clamp.

constexpr int Nn = 1024;
constexpr int Kk = 64;
constexpr float LOG2E = 1.4426950408889634f;
constexpr float LN2   = 0.6931471805599453f;

typedef float f32x4  __attribute__((ext_vector_type(4)));
typedef _Float16 half8 __attribute__((ext_vector_type(8)));
typedef int   int32x4 __attribute__((ext_vector_type(4)));

__device__ __forceinline__ float fast_exp2(float x) {
#if __has_builtin(__builtin_amdgcn_exp2f)
    return __builtin_amdgcn_exp2f(x);
#else
    return exp2f(x);
#endif
}

__device__ __forceinline__ int pkrtz(float lo, float hi) {
    return __builtin_bit_cast(int, __builtin_amdgcn_cvt_pkrtz(lo, hi));
}

// A fragment (E^T) for tile (mt,kt): q-th f16 = exp(trans[k][m]),
// k = kt*32 + psi(blk,q), psi = (q>>2)*16 + 4*blk + (q&3), m = mt*16+n.
__device__ __forceinline__ half8 load_afrag(const float* __restrict__ trans,
                                            int n, int blk, int mt, int kt) {
    half8 r;
#pragma unroll
    for (int q = 0; q < 8; ++q) {
        int k = kt * 32 + (q >> 2) * 16 + 4 * blk + (q & 3);
        float v = fast_exp2(trans[k * Kk + mt * 16 + n] * LOG2E);
        r[q] = (_Float16)v;   // RNE
    }
    return r;
}

__device__ __forceinline__ int clamp_s(int s) {
    return s < -100 ? -100 : (s > 100 ? 100 : s);
}

// stage one step's emits: 4 x global_load_lds(16B), lane-private chunks.
__device__ __forceinline__ void stage4(const float* src, float* dstbase) {
#pragma unroll
    for (int mt = 0; mt < 4; ++mt) {
        __builtin_amdgcn_global_load_lds(
            (const __attribute__((address_space(1))) unsigned*)(src + mt * 16),
            (__attribute__((address_space(3))) unsigned*)(dstbase + mt * 256),
            16, 0, 0);
    }
}

#define MFMA16(a, b, c) __builtin_amdgcn_mfma_f32_16x16x32_f16((a), (b), (c), 0, 0, 0)

__global__ __launch_bounds__(64, 1) void crf_fwd(
    const float* __restrict__ y_pred,   // [B,N,K]
    const float* __restrict__ trans,    // [K,K]
    float* __restrict__ out)            // [B], pre-loaded with -target
{
    const int l   = threadIdx.x;
    const int n   = l & 15;
    const int blk = l >> 4;

    __shared__ __align__(16) float lds[16 * 1024];  // [chain][slot][1024]

    const float* ypA = y_pred + (size_t)(blockIdx.x * 32 + n)      * (Nn * Kk);
    const float* ypB = y_pred + (size_t)(blockIdx.x * 32 + 16 + n) * (Nn * Kk);
    const float* ypnA = ypA + 4 * blk;
    const float* ypnB = ypB + 4 * blk;

    // shared constant A fragments (E^T), 8 x half8 = 32 VGPRs
    half8 a00 = load_afrag(trans, n, blk, 0, 0), a01 = load_afrag(trans, n, blk, 0, 1);
    half8 a10 = load_afrag(trans, n, blk, 1, 0), a11 = load_afrag(trans, n, blk, 1, 1);
    half8 a20 = load_afrag(trans, n, blk, 2, 0), a21 = load_afrag(trans, n, blk, 2, 1);
    half8 a30 = load_afrag(trans, n, blk, 3, 0), a31 = load_afrag(trans, n, blk, 3, 1);

    // ---- t = 0 init, per chain ----
#define INIT_CHAIN(S, YPN, YP) \
    f32x4 c0##S, c1##S, c2##S, c3##S; \
    { \
        f32x4 e0 = *(const f32x4*)(YPN); \
        f32x4 e1 = *(const f32x4*)(YPN + 16); \
        f32x4 e2 = *(const f32x4*)(YPN + 32); \
        f32x4 e3 = *(const f32x4*)(YPN + 48); \
        float M0_ = (YP)[0]; \
        c0##S.x = fast_exp2((e0.x - M0_) * LOG2E); c0##S.y = fast_exp2((e0.y - M0_) * LOG2E); \
        c0##S.z = fast_exp2((e0.z - M0_) * LOG2E); c0##S.w = fast_exp2((e0.w - M0_) * LOG2E); \
        c1##S.x = fast_exp2((e1.x - M0_) * LOG2E); c1##S.y = fast_exp2((e1.y - M0_) * LOG2E); \
        c1##S.z = fast_exp2((e1.z - M0_) * LOG2E); c1##S.w = fast_exp2((e1.w - M0_) * LOG2E); \
        c2##S.x = fast_exp2((e2.x - M0_) * LOG2E); c2##S.y = fast_exp2((e2.y - M0_) * LOG2E); \
        c2##S.z = fast_ex2_dummy_ ## S ## _unused(0); \
    }
    // (macro above intentionally not used - INIT expanded manually below for clarity)
#undef INIT_CHAIN

    f32x4 c0A, c1A, c2A, c3A, c0B, c1B, c2B, c3B;
    {
        f32x4 e0 = *(const f32x4*)(ypnA);
        f32x4 e1 = *(const f32x4*)(ypnA + 16);
        f32x4 e2 = *(const f32x4*)(ypnA + 32);
        f32x4 e3 = *(const f32x4*)(ypnA + 48);
        float M0_ = ypA[0];
        c0A.x = fast_exp2((e0.x - M0_) * LOG2E); c0A.y = fast_exp2((e0.y - M0_) * LOG2E);
        c0A.z = fast_exp2((e0.z - M0_) * LOG2E); c0A.w = fast_exp2((e0.w - M0_) * LOG2E);
        c1A.x = fast_exp2((e1.x - M0_) * LOG2E); c1A.y = fast_exp2((e1.y - M0_) * LOG2E);
        c1A.z = fast_exp2((e1.z - M0_) * LOG2E); c1A.w = fast_exp2((e1.w - M0_) * LOG2E);
        c2A.x = fast_exp2((e2.x - M0_) * LOG2E); c2A.y = fast_exp2((e2.y - M0_) * LOG2E);
        c2A.z = fast_exp2((e2.z - M0_) * LOG2E); c2A.w = fast_exp2((e2.w - M0_) * LOG2E);
        c3A.x = fast_exp2((e3.x - M0_) * LOG2E); c3A.y = fast_exp2((e3.y - M0_) * LOG2E);
        c3A.z = fast_exp2((e3.z - M0_) * LOG2E); c3A.w = fast_exp2((e3.w - M0_) * LOG2E);
    }
    {
        f32x4 e0 = *(const f32x4*)(ypnB);
        f32x4 e1 = *(const f32x4*)(ypnB + 16);
        f32x4 e2 = *(const f32x4*)(ypnB + 32);
        f32x4 e3 = *(const f32x4*)(ypnB + 48);
        float M0_ = ypB[0];
        c0B.x = fast_exp2((e0.x - M0_) * LOG2E); c0B.y = fast_exp2((e0.y - M0_) * LOG2E);
        c0B.z = fast_exp2((e0.z - M0_) * LOG2E); c0B.w = fast_exp2((e0.w - M0_) * LOG2E);
        c1B.x = fast_exp2((e1.x - M0_) * LOG2E); c1B.y = fast_exp2((e1.y - M0_) * LOG2E);
        c1B.z = fast_exp2((e1.z - M0_) * LOG2E); c1B.w = fast_exp2((e1.w - M0_) * LOG2E);
        c2B.x = fast_exp2((e2.x - M0_) * LOG2E); c2B.y = fast_exp2((e2.y - M0_) * LOG2E);
        c2B.z = fast_exp2((e2.z - M0_) * LOG2E); c2B.w = fast_exp2((e2.w - M0_) * LOG2E);
        c3B.x = fast_exp2((e3.x - M0_) * LOG2E); c3B.y = fast_exp2((e3.y - M0_) * LOG2E);
        c3B.z = fast_exp2((e3.z - M0_) * LOG2E); c3B.w = fast_exp2((e3.w - M0_) * LOG2E);
    }
    const float M0A = ypA[0];
    const float M0B = ypB[0];

    half8 b0A = __builtin_bit_cast(half8, (int32x4){pkrtz(c0A.x, c0A.y), pkrtz(c0A.z, c0A.w),
                                                    pkrtz(c1A.x, c1A.y), pkrtz(c1A.z, c1A.w)});
    half8 b1A = __builtin_bit_cast(half8, (int32x4){pkrtz(c2A.x, c2A.y), pkrtz(c2A.z, c2A.w),
                                                    pkrtz(c3A.x, c3A.y), pkrtz(c3A.z, c3A.w)});
    half8 b0B = __builtin_bit_cast(half8, (int32x4){pkrtz(c0B.x, c0B.y), pkrtz(c0B.z, c0B.w),
                                                    pkrtz(c1B.x, c1B.y), pkrtz(c1B.z, c1B.w)});
    half8 b1B = __builtin_bit_cast(half8, (int32x4){pkrtz(c2B.x, c2B.y), pkrtz(c2B.z, c2B.w),
                                                    pkrtz(c3B.x, c3B.y), pkrtz(c3B.z, c3B.w)});

    int s_useA, s_useB;
    {
        float vA = __shfl(c0A.x, n);
        s_useA = clamp_s((int)((__builtin_bit_cast(unsigned, vA) >> 23) & 0xFFu) - 127);
        float vB = __shfl(c0B.x, n);
        s_useB = clamp_s((int)((__builtin_bit_cast(unsigned, vB) >> 23) & 0xFFu) - 127);
    }
    int SaccA = 0, SaccB = 0;

    // drain setup loads so the vmcnt ring count is exact
    asm volatile("s_waitcnt vmcnt(0)" ::: "memory");

    // prologue: stage slots t=1..7 for both chains (56 loads in flight)
#pragma unroll
    for (int t = 1; t <= 7; ++t) {
        stage4(ypnA + t * 64, &lds[(t & 7) * 1024]);
        stage4(ypnB + t * 64, &lds[8 * 1024 + (t & 7) * 1024]);
    }

    // read slot 1 for both chains; 48 loads remain outstanding
    asm volatile("s_waitcnt vmcnt(48)" ::: "memory");
    f32x4 emcA0, emcA1, emcA2, emcA3, emnA0, emnA1, emnA2, emnA3;
    f32x4 emcB0, emcB1, emcB2, emcB3, emnB0, emnB1, emnB2, emnB3;
    {
        const float* ea = &lds[1 * 1024] + l * 4;
        emcA0 = *(const f32x4*)(ea);       emcA1 = *(const f32x4*)(ea + 256);
        emcA2 = *(const f32x4*)(ea + 512); emcA3 = *(const f32x4*)(ea + 768);
        const float* eb = &lds[8 * 1024 + 1 * 1024] + l * 4;
        emcB0 = *(const f32x4*)(eb);       emcB1 = *(const f32x4*)(eb + 256);
        emcB2 = *(const f32x4*)(eb + 512); emcB3 = *(const f32x4*)(eb + 768);
    }

    const float CHI = 60000.0f;   // f16-inf guard

#define PE1(S, CN, EM, MSU) \
    c##CN##S.x = fminf(d##CN##S.x * fast_exp2(fmaf(EM.x, LOG2E, MSU)), CHI); \
    c##CN##S.y = fminf(d##CN##S.y * fast_exp2(fmaf(EM.y, LOG2E, MSU)), CHI); \
    c##CN##S.z = fminf(d##CN##S.z * fast_exp2(fmaf(EM.z, LOG2E, MSU)), CHI); \
    c##CN##S.w = fminf(d##CN##S.w * fast_exp2(fmaf(EM.w, LOG2E, MSU)), CHI);

// one dual-chain step: T = time index; EI*/EO* emit reg names per chain
#define STEP2(T, AI0, AI1, AI2, AI3, AO0, AO1, AO2, AO3, \
                 BI0, BI1, BI2, BI3, BO0, BO1, BO2, BO3) { \
    f32x4 zz_ = {0.f, 0.f, 0.f, 0.f}; \
    f32x4 d0A = MFMA16(a00, b0A, MFMA16(a01, b1A, zz_)); \
    f32x4 d0B = MFMA16(a00, b0B, MFMA16(a01, b1B, zz_)); \
    f32x4 d1A = MFMA16(a10, b0A, MFMA16(a11, b1A, zz_)); \
    f32x4 d1B = MFMA16(a10, b0B, MFMA16(a11, b1B, zz_)); \
    f32x4 d2A = MFMA16(a20, b0A, MFMA16(a21, b1A, zz_)); \
    f32x4 d2B = MFMA16(a20, b0B, MFMA16(a21, b1B, zz_)); \
    f32x4 d3A = MFMA16(a30, b0A, MFMA16(a31, b1A, zz_)); \
    f32x4 d3B = MFMA16(a30, b0B, MFMA16(a31, b1B, zz_)); \
    asm volatile("s_waitcnt vmcnt(40)" ::: "memory"); \
    { const float* na_ = &lds[(((T) + 1) & 7) * 1024] + l * 4; \
      AO0 = *(const f32x4*)(na_);       AO1 = *(const f32x4*)(na_ + 256); \
      AO2 = *(const f32x4*)(na_ + 512); AO3 = *(const f32x4*)(na_ + 768); \
      const float* nb_ = &lds[8 * 1024 + (((T) + 1) & 7) * 1024] + l * 4; \
      BO0 = *(const f32x4*)(nb_);       BO1 = *(const f32x4*)(nb_ + 256); \
      BO2 = *(const f32x4*)(nb_ + 512); BO3 = *(const f32x4*)(nb_ + 768); } \
    float msuA_ = -(float)s_useA; SaccA += s_useA; \
    float msuB_ = -(float)s_useB; SaccB += s_useB; \
    PE1(A, 0, AI0, msuA_) \
    float bcA_ = __shfl(c0A.x, n); \
    PE1(B, 0, BI0, msuB_) \
    float bcB_ = __shfl(c0B.x, n); \
    PE1(A, 1, AI1, msuA_) PE1(A, 2, AI2, msuA_) PE1(A, 3, AI3, msuA_) \
    PE1(B, 1, BI1, msuB_) PE1(B, 2, BI2, msuB_) PE1(B, 3, BI3, msuB_) \
    s_useA = clamp_s((int)((__builtin_bit_cast(unsigned, bcA_) >> 23) & 0xFFu) - 127); \
    s_useB = clamp_s((int)((__builtin_bit_cast(unsigned, bcB_) >> 23) & 0xFFu) - 127); \
    asm volatile("" ::: "memory"); \
    { int ts_ = (T) + 7 > Nn - 1 ? Nn - 1 : (T) + 7; \
      stage4(ypnA + ts_ * 64, &lds[(ts_ & 7) * 1024]); \
      stage4(ypnB + ts_ * 64, &lds[8 * 1024 + (ts_ & 7) * 1024]); } \
    b0A = __builtin_bit_cast(half8, (int32x4){pkrtz(c0A.x, c0A.y), pkrtz(c0A.z, c0A.w), \
                                              pkrtz(c1A.x, c1A.y), pkrtz(c1A.z, c1A.w)}); \
    b1A = __builtin_bit_cast(half8, (int32x4){pkrtz(c2A.x, c2A.y), pkrtz(c2A.z, c2A.w), \
                                              pkrtz(c3A.x, c3A.y), pkrtz(c3A.z, c3A.w)}); \
    b0B = __builtin_bit_cast(half8, (int32x4){pkrtz(c0B.x, c0B.y), pkrtz(c0B.z, c0B.w), \
                                              pkrtz(c1B.x, c1B.y), pkrtz(c1B.z, c1B.w)}); \
    b1B = __builtin_bit_cast(half8, (int32x4){pkrtz(c2B.x, c2B.y), pkrtz(c2B.z, c2B.w), \
                                              pkrtz(c3B.x, c3B.y), pkrtz(c3B.z, c3B.w)}); \
}

    // t = 1..1022 in 511 static cur/next pairs
    for (int tb = 0; tb < 511; ++tb) {
        const int t = 2 * tb + 1;
        STEP2(t,     emcA0, emcA1, emcA2, emcA3, emnA0, emnA1, emnA2, emnA3,
                     emcB0, emcB1, emcB2, emcB3, emnB0, emnB1, emnB2, emnB3)
        STEP2(t + 1, emnA0, emnA1, emnA2, emnA3, emcA0, emcA1, emcA2, emcA3,
                     emnB0, emnB1, emnB2, emnB3, emcB0, emcB1, emcB2, emcB3)
    }
    // tail t = 1023
    STEP2(1023, emcA0, emcA1, emcA2, emcA3, emnA0, emnA1, emnA2, emnA3,
                emcB0, emcB1, emcB2, emcB3, emnB0, emnB1, emnB2, emnB3)

    // drain outstanding DMA before endpgm
    asm volatile("s_waitcnt vmcnt(0)" ::: "memory");

    // epilogue: log_norm per column, both chains
    float sumA = ((c0A.x + c0A.y) + (c0A.z + c0A.w)) + ((c1A.x + c1A.y) + (c1A.z + c1A.w))
               + ((c2A.x + c2A.y) + (c2A.z + c2A.w)) + ((c3A.x + c3A.y) + (c3A.z + c3A.w));
    sumA += __shfl_xor(sumA, 16);
    sumA += __shfl_xor(sumA, 32);
    float lnA = (log2f(sumA) + (float)SaccA) * LN2 + M0A;

    float sumB = ((c0B.x + c0B.y) + (c0B.z + c0B.w)) + ((c1B.x + c1B.y) + (c1B.z + c1B.w))
               + ((c2B.x + c2B.y) + (c2B.z + c2B.w)) + ((c3B.x + c3B.y) + (c3B.z + c3B.w));
    sumB += __shfl_xor(sumB, 16);
    sumB += __shfl_xor(sumB, 32);
    float lnB = (log2f(sumB) + (float)SaccB) * LN2 + M0B;

    if (l < 16) {
        out[blockIdx.x * 32 + l] += lnA;
    } else if (l < 32) {
        out[blockIdx.x * 32 + 16 + (l & 15)] += lnB;
    }
}

// target_score kernel: out[b] = -(point + trans-pairs). One wave per row.
__global__ __launch_bounds__(64) void crf_target(
    const float* __restrict__ y_pred,
    const float* __restrict__ trans,
    const int*   __restrict__ y_true,
    float* __restrict__ out)
{
    const int b = blockIdx.x, l = threadIdx.x;
    const int* ytb = y_true + (size_t)b * Nn;
    const float* ypb = y_pred + (size_t)b * Nn * Kk;
    float v = 0.0f;
#pragma unroll
    for (int i = 0; i < 16; ++i) {
        int t = i * 64 + l;
        int y0 = ytb[t];
        v += ypb[(size_t)t * Kk + y0];
        if (t < Nn - 1) {
            int y1 = ytb[t + 1];
            v += trans[y0 * Kk + y1];
        }
    }
#pragma unroll
    for (int off = 32; off; off >>= 1) v += __shfl_xor(v, off);
    if (l == 0) out[b] = -v;
}

extern "C" void kernel_launch(void* const* d_in, const int* in_sizes, int n_in,
                              void* d_out, int out_size, void* d_ws, size_t ws_size,
                              hipStream_t stream) {
    const float* y_pred = (const float*)d_in[0];
    const float* trans  = (const float*)d_in[1];
    const int*   y_true = (const int*)d_in[2];
    float* out = (float*)d_out;

    crf_target<<<512, 64, 0, stream>>>(y_pred, trans, y_true, out);
    crf_fwd<<<16, 64, 0, stream>>>(y_pred, trans, out);
}

// Round 14
// 305.489 us; speedup vs baseline: 1.8859x; 1.8859x over previous
//
#include <hip/hip_runtime.h>
#include <cstdint>
#include <cstddef>

// CRF loss: out[b] = log_norm(b) - target_score(b).  B=512, N=1024, K=64.
//
// R14 vs R13/R11: R13 (dual-chain 1.82x time) proved the step cost is
// wave-serial ISSUE, not per-chain stall. Biggest issue item: 16x
// quarter-rate v_exp_f32 per step (~128 cyc) + its latency on the d->b
// chain. Fix: precompute pe = exp(y_pred) in a massively parallel
// memory-bound pass into d_ws (~45us), and reduce the scan PE to
// c = min(d * (pe * 2^-s), CHI): prescale muls hide in the MFMA shadow,
// critical path = mul -> min -> pkrtz. Host checks ws_size >= 134MB;
// else falls back to the R11-identical in-loop-exp2 path (known-good).
//
// Scan layout unchanged (R11): one wave = 16 rows, 8x mfma_16x16x32_f16
// per step, psi(blk,q) A-map, lag-1 pow2 rescale via __shfl, 8-slot LDS
// emit ring staged by global_load_lds, counted vmcnt(24|28) waits.

constexpr int Nn = 1024;
constexpr int Kk = 64;
constexpr float LOG2E = 1.4426950408889634f;
constexpr float LN2   = 0.6931471805599453f;

typedef float f32x4  __attribute__((ext_vector_type(4)));
typedef _Float16 half8 __attribute__((ext_vector_type(8)));
typedef int   int32x4 __attribute__((ext_vector_type(4)));

__device__ __forceinline__ float fast_exp2(float x) {
#if __has_builtin(__builtin_amdgcn_exp2f)
    return __builtin_amdgcn_exp2f(x);
#else
    return exp2f(x);
#endif
}

__device__ __forceinline__ int pkrtz(float lo, float hi) {
    return __builtin_bit_cast(int, __builtin_amdgcn_cvt_pkrtz(lo, hi));
}

// A fragment (E^T) for tile (mt,kt): q-th f16 = exp(trans[k][m]),
// k = kt*32 + psi(blk,q), psi = (q>>2)*16 + 4*blk + (q&3), m = mt*16+n.
__device__ __forceinline__ half8 load_afrag(const float* __restrict__ trans,
                                            int n, int blk, int mt, int kt) {
    half8 r;
#pragma unroll
    for (int q = 0; q < 8; ++q) {
        int k = kt * 32 + (q >> 2) * 16 + 4 * blk + (q & 3);
        float v = fast_exp2(trans[k * Kk + mt * 16 + n] * LOG2E);
        r[q] = (_Float16)v;   // RNE
    }
    return r;
}

__device__ __forceinline__ int clamp_s(int s) {
    return s < -100 ? -100 : (s > 100 ? 100 : s);
}

// stage one step's stream data: 4 x global_load_lds(16B), lane-private.
__device__ __forceinline__ void stage4(const float* src, float* dstbase) {
#pragma unroll
    for (int mt = 0; mt < 4; ++mt) {
        __builtin_amdgcn_global_load_lds(
            (const __attribute__((address_space(1))) unsigned*)(src + mt * 16),
            (__attribute__((address_space(3))) unsigned*)(dstbase + mt * 256),
            16, 0, 0);
    }
}

#define MFMA16(a, b, c) __builtin_amdgcn_mfma_f32_16x16x32_f16((a), (b), (c), 0, 0, 0)

// pe precompute: pe[i] = exp(y_pred[i]); pure elementwise, memory-bound.
__global__ __launch_bounds__(256) void crf_exp(
    const float* __restrict__ in, float* __restrict__ o)
{
    const f32x4* iv = (const f32x4*)in;
    f32x4* ov = (f32x4*)o;
    const int total4 = 8388608;   // 512*1024*64 / 4
    int i = blockIdx.x * 256 + threadIdx.x;
    const int stride = gridDim.x * 256;
    for (; i < total4; i += stride) {
        f32x4 v = iv[i];
        f32x4 r;
        r.x = fast_exp2(v.x * LOG2E);
        r.y = fast_exp2(v.y * LOG2E);
        r.z = fast_exp2(v.z * LOG2E);
        r.w = fast_exp2(v.w * LOG2E);
        ov[i] = r;
    }
}

template<bool USE_PE>
__global__ __launch_bounds__(64, 1) void crf_fwd(
    const float* __restrict__ y_pred,   // [B,N,K] raw logits
    const float* __restrict__ stream,   // USE_PE ? pe buffer : y_pred
    const float* __restrict__ trans,    // [K,K]
    float* __restrict__ out)            // [B], pre-loaded with -target
{
    const int l   = threadIdx.x;
    const int n   = l & 15;
    const int blk = l >> 4;

    __shared__ __align__(16) float lds[8 * 1024];   // 8 slots x 4KB

    const float* yp  = y_pred + (size_t)(blockIdx.x * 16 + n) * (Nn * Kk);
    const float* ypn = yp + 4 * blk;
    const float* spn = stream + (size_t)(blockIdx.x * 16 + n) * (Nn * Kk) + 4 * blk;

    // constant A fragments (E^T), 8 x half8 = 32 VGPRs
    half8 a00 = load_afrag(trans, n, blk, 0, 0), a01 = load_afrag(trans, n, blk, 0, 1);
    half8 a10 = load_afrag(trans, n, blk, 1, 0), a11 = load_afrag(trans, n, blk, 1, 1);
    half8 a20 = load_afrag(trans, n, blk, 2, 0), a21 = load_afrag(trans, n, blk, 2, 1);
    half8 a30 = load_afrag(trans, n, blk, 3, 0), a31 = load_afrag(trans, n, blk, 3, 1);

    // ---- t = 0: C = exp(y_pred[:,0] - M0), from raw logits
    f32x4 c0, c1, c2, c3;
    {
        f32x4 e0 = *(const f32x4*)(ypn);
        f32x4 e1 = *(const f32x4*)(ypn + 16);
        f32x4 e2 = *(const f32x4*)(ypn + 32);
        f32x4 e3 = *(const f32x4*)(ypn + 48);
        float M0_ = yp[0];
        c0.x = fast_exp2((e0.x - M0_) * LOG2E); c0.y = fast_exp2((e0.y - M0_) * LOG2E);
        c0.z = fast_exp2((e0.z - M0_) * LOG2E); c0.w = fast_exp2((e0.w - M0_) * LOG2E);
        c1.x = fast_exp2((e1.x - M0_) * LOG2E); c1.y = fast_exp2((e1.y - M0_) * LOG2E);
        c1.z = fast_exp2((e1.z - M0_) * LOG2E); c1.w = fast_exp2((e1.w - M0_) * LOG2E);
        c2.x = fast_exp2((e2.x - M0_) * LOG2E); c2.y = fast_exp2((e2.y - M0_) * LOG2E);
        c2.z = fast_exp2((e2.z - M0_) * LOG2E); c2.w = fast_exp2((e2.w - M0_) * LOG2E);
        c3.x = fast_exp2((e3.x - M0_) * LOG2E); c3.y = fast_exp2((e3.y - M0_) * LOG2E);
        c3.z = fast_exp2((e3.z - M0_) * LOG2E); c3.w = fast_exp2((e3.w - M0_) * LOG2E);
    }
    const float M0 = yp[0];

    half8 b0 = __builtin_bit_cast(half8, (int32x4){pkrtz(c0.x, c0.y), pkrtz(c0.z, c0.w),
                                                   pkrtz(c1.x, c1.y), pkrtz(c1.z, c1.w)});
    half8 b1 = __builtin_bit_cast(half8, (int32x4){pkrtz(c2.x, c2.y), pkrtz(c2.z, c2.w),
                                                   pkrtz(c3.x, c3.y), pkrtz(c3.z, c3.w)});

    int s_use;
    {
        float v = __shfl(c0.x, n);
        s_use = clamp_s((int)((__builtin_bit_cast(unsigned, v) >> 23) & 0xFFu) - 127);
    }
    int Sacc = 0;

    // drain setup loads so the vmcnt ring count is exact
    asm volatile("s_waitcnt vmcnt(0)" ::: "memory");

    // prologue: stage slots for t=1..8 (32 loads in flight)
#pragma unroll
    for (int t = 1; t <= 8; ++t) {
        stage4(spn + t * 64, &lds[(t & 7) * 1024]);
    }

    asm volatile("s_waitcnt vmcnt(28)" ::: "memory");
    f32x4 emc0, emc1, emc2, emc3, emn0, emn1, emn2, emn3;
    {
        const float* eb = &lds[1 * 1024] + l * 4;
        emc0 = *(const f32x4*)(eb);       emc1 = *(const f32x4*)(eb + 256);
        emc2 = *(const f32x4*)(eb + 512); emc3 = *(const f32x4*)(eb + 768);
    }

    const float CHI = 60000.0f;   // f16-inf guard

#define PE_OLD(CN, EM) \
    c##CN.x = fminf(d##CN.x * fast_exp2(fmaf(EM.x, LOG2E, msu_)), CHI); \
    c##CN.y = fminf(d##CN.y * fast_exp2(fmaf(EM.y, LOG2E, msu_)), CHI); \
    c##CN.z = fminf(d##CN.z * fast_exp2(fmaf(EM.z, LOG2E, msu_)), CHI); \
    c##CN.w = fminf(d##CN.w * fast_exp2(fmaf(EM.w, LOG2E, msu_)), CHI);

#define PE_NEW(CN, PS) \
    c##CN.x = fminf(d##CN.x * PS.x, CHI); \
    c##CN.y = fminf(d##CN.y * PS.y, CHI); \
    c##CN.z = fminf(d##CN.z * PS.z, CHI); \
    c##CN.w = fminf(d##CN.w * PS.w, CHI);

#define STEP(T, EI0, EI1, EI2, EI3, EO0, EO1, EO2, EO3) { \
    f32x4 zz_ = {0.f, 0.f, 0.f, 0.f}; \
    f32x4 d0 = MFMA16(a00, b0, MFMA16(a01, b1, zz_)); \
    f32x4 d1 = MFMA16(a10, b0, MFMA16(a11, b1, zz_)); \
    f32x4 d2 = MFMA16(a20, b0, MFMA16(a21, b1, zz_)); \
    f32x4 d3 = MFMA16(a30, b0, MFMA16(a31, b1, zz_)); \
    asm volatile("s_waitcnt vmcnt(24)" ::: "memory"); \
    { const float* nb_ = &lds[(((T) + 1) & 7) * 1024] + l * 4; \
      EO0 = *(const f32x4*)(nb_);       EO1 = *(const f32x4*)(nb_ + 256); \
      EO2 = *(const f32x4*)(nb_ + 512); EO3 = *(const f32x4*)(nb_ + 768); } \
    Sacc += s_use; \
    if constexpr (USE_PE) { \
        float s2p_ = __builtin_bit_cast(float, (unsigned)(127 - s_use) << 23); \
        f32x4 ps0, ps1, ps2, ps3; \
        ps0.x = EI0.x * s2p_; ps0.y = EI0.y * s2p_; ps0.z = EI0.z * s2p_; ps0.w = EI0.w * s2p_; \
        ps1.x = EI1.x * s2p_; ps1.y = EI1.y * s2p_; ps1.z = EI1.z * s2p_; ps1.w = EI1.w * s2p_; \
        ps2.x = EI2.x * s2p_; ps2.y = EI2.y * s2p_; ps2.z = EI2.z * s2p_; ps2.w = EI2.w * s2p_; \
        ps3.x = EI3.x * s2p_; ps3.y = EI3.y * s2p_; ps3.z = EI3.z * s2p_; ps3.w = EI3.w * s2p_; \
        PE_NEW(0, ps0) \
        float bc_ = __shfl(c0.x, n); \
        PE_NEW(1, ps1) PE_NEW(2, ps2) PE_NEW(3, ps3) \
        s_use = clamp_s((int)((__builtin_bit_cast(unsigned, bc_) >> 23) & 0xFFu) - 127); \
    } else { \
        float msu_ = -(float)s_use; \
        PE_OLD(0, EI0) \
        float bc_ = __shfl(c0.x, n); \
        PE_OLD(1, EI1) PE_OLD(2, EI2) PE_OLD(3, EI3) \
        s_use = clamp_s((int)((__builtin_bit_cast(unsigned, bc_) >> 23) & 0xFFu) - 127); \
    } \
    asm volatile("" ::: "memory"); \
    { int ts_ = (T) + 8 > Nn - 1 ? Nn - 1 : (T) + 8; \
      stage4(spn + ts_ * 64, &lds[((T) & 7) * 1024]); } \
    b0 = __builtin_bit_cast(half8, (int32x4){pkrtz(c0.x, c0.y), pkrtz(c0.z, c0.w), \
                                             pkrtz(c1.x, c1.y), pkrtz(c1.z, c1.w)}); \
    b1 = __builtin_bit_cast(half8, (int32x4){pkrtz(c2.x, c2.y), pkrtz(c2.z, c2.w), \
                                             pkrtz(c3.x, c3.y), pkrtz(c3.z, c3.w)}); \
}

    // t = 1..1022 in 511 static cur/next pairs
    for (int tb = 0; tb < 511; ++tb) {
        const int t = 2 * tb + 1;
        STEP(t,     emc0, emc1, emc2, emc3, emn0, emn1, emn2, emn3)
        STEP(t + 1, emn0, emn1, emn2, emn3, emc0, emc1, emc2, emc3)
    }
    // tail t = 1023
    STEP(1023, emc0, emc1, emc2, emc3, emn0, emn1, emn2, emn3)

    asm volatile("s_waitcnt vmcnt(0)" ::: "memory");

    // epilogue: log_norm per column
    float sum = ((c0.x + c0.y) + (c0.z + c0.w)) + ((c1.x + c1.y) + (c1.z + c1.w))
              + ((c2.x + c2.y) + (c2.z + c2.w)) + ((c3.x + c3.y) + (c3.z + c3.w));
    sum += __shfl_xor(sum, 16);
    sum += __shfl_xor(sum, 32);
    float log_norm = (log2f(sum) + (float)Sacc) * LN2 + M0;
    if (l < 16) {
        out[blockIdx.x * 16 + l] += log_norm;   // out pre-holds -target
    }
}

// target_score kernel: out[b] = -(point + trans-pairs). One wave per row.
__global__ __launch_bounds__(64) void crf_target(
    const float* __restrict__ y_pred,
    const float* __restrict__ trans,
    const int*   __restrict__ y_true,
    float* __restrict__ out)
{
    const int b = blockIdx.x, l = threadIdx.x;
    const int* ytb = y_true + (size_t)b * Nn;
    const float* ypb = y_pred + (size_t)b * Nn * Kk;
    float v = 0.0f;
#pragma unroll
    for (int i = 0; i < 16; ++i) {
        int t = i * 64 + l;
        int y0 = ytb[t];
        v += ypb[(size_t)t * Kk + y0];
        if (t < Nn - 1) {
            int y1 = ytb[t + 1];
            v += trans[y0 * Kk + y1];
        }
    }
#pragma unroll
    for (int off = 32; off; off >>= 1) v += __shfl_xor(v, off);
    if (l == 0) out[b] = -v;
}

extern "C" void kernel_launch(void* const* d_in, const int* in_sizes, int n_in,
                              void* d_out, int out_size, void* d_ws, size_t ws_size,
                              hipStream_t stream) {
    const float* y_pred = (const float*)d_in[0];
    const float* trans  = (const float*)d_in[1];
    const int*   y_true = (const int*)d_in[2];
    float* out = (float*)d_out;

    const size_t pe_bytes = (size_t)512 * 1024 * 64 * 4;   // 134 MB
    const bool use_pe = (ws_size >= pe_bytes) && (d_ws != nullptr);

    crf_target<<<512, 64, 0, stream>>>(y_pred, trans, y_true, out);
    if (use_pe) {
        crf_exp<<<2048, 256, 0, stream>>>(y_pred, (float*)d_ws);
        crf_fwd<true><<<32, 64, 0, stream>>>(y_pred, (const float*)d_ws, trans, out);
    } else {
        crf_fwd<false><<<32, 64, 0, stream>>>(y_pred, y_pred, trans, out);
    }
}